// Round 10
// baseline (448.928 us; speedup 1.0000x reference)
//
#include <hip/hip_runtime.h>

#define CH 128
#define NCLS 16
#define CHK 16          // channels per chunk
#define NCHUNK 8        // 8 chunks of 16 == 128 channels, one per XCD
#define ECAP 131072     // bucket capacity per partition (E/8 = 100k expected)
#define NBLD 512        // persistent build blocks (2/CU -- co-residency safe)

typedef __attribute__((ext_vector_type(8))) short bf16x8;
typedef __attribute__((ext_vector_type(4))) float f32x4;

__device__ inline ushort f2bf(float f) {        // RTNE fp32 -> bf16 bits
    unsigned u = __float_as_uint(f);
    unsigned r = u + 0x7fffu + ((u >> 16) & 1u);
    return (ushort)(r >> 16);
}
__device__ inline float bf2f(ushort b) {
    return __uint_as_float(((unsigned)b) << 16);
}

// one-shot grid barrier; ctr pre-zeroed by hipMemsetAsync. ALL NBLD blocks
// are co-resident (launch_bounds(256,2) => 2 blocks/CU, 512 == 2*256), so
// spin-wait cannot starve (the R8 failure needed blocks > capacity).
__device__ __forceinline__ void gridbar(int* ctr, int nb) {
    __syncthreads();
    if (threadIdx.x == 0) {
        __threadfence();
        __hip_atomic_fetch_add(ctr, 1, __ATOMIC_RELEASE, __HIP_MEMORY_SCOPE_AGENT);
        while (__hip_atomic_load(ctr, __ATOMIC_ACQUIRE, __HIP_MEMORY_SCOPE_AGENT) < nb)
            __builtin_amdgcn_s_sleep(1);
        __threadfence();
    }
    __syncthreads();
}

// ------------------------------------------------- persistent build kernel
// Phase A (prep): weight hi/lo split, zero cnt/pcnt/galloc, bufA row n.
// Phase B (bucket+count): ONE edge pass -> 8 dst-partition buckets + degree
// histogram (LDS-aggregated bucket cursors; 8 global atomics/block/pass).
// Phase C (place): dense-CSR region allocator, block-local LDS scan +
// 1 global atomicAdd; self-edge + pads written here.
// Fusing prep/bucket/place removes 2 kernel boundaries (drain+flush each).
__global__ __launch_bounds__(256, 2) void build_kernel(
    const float* __restrict__ W1, const float* __restrict__ W2,
    ushort* __restrict__ w1hi, ushort* __restrict__ w1lo,
    ushort* __restrict__ w2hi, ushort* __restrict__ w2lo,
    const int* __restrict__ src, const int* __restrict__ dst,
    unsigned* __restrict__ ebuf, int* __restrict__ pcnt,
    int* __restrict__ cnt, int* __restrict__ rsp, int* __restrict__ cursor,
    int* __restrict__ galloc, ushort* __restrict__ esrc,
    float* __restrict__ bufA, int* __restrict__ bars,
    int n, int E, float p8n, int nbz) {
    __shared__ int lpos[8];
    __shared__ int lbase[8];
    __shared__ int lds[256];
    __shared__ int gbase;
    const int b = blockIdx.x, tid = threadIdx.x;

    // ---------------- phase A
    if (b < 128) {
        const float* W = (b < 64) ? W1 : W2;
        ushort* Whi = (b < 64) ? w1hi : w2hi;
        ushort* Wlo = (b < 64) ? w1lo : w2lo;
        int t = ((b & 63) << 8) + tid;
        int k = t >> 7, nn = t & 127;
        float v = W[t];
        ushort h = f2bf(v);
        Whi[nn * CH + k] = h;
        Wlo[nn * CH + k] = f2bf(v - bf2f(h));
    }
    for (int i = b * 256 + tid; i < n; i += NBLD * 256) cnt[i] = 0;
    if (b == 128) {
        if (tid < NCHUNK * CHK) {
            int c = tid >> 4, ch = tid & 15;
            bufA[((size_t)c * (n + 1) + n) * CHK + ch] = 0.0f;
        }
        if (tid < 8) pcnt[tid] = 0;
        if (tid == 8) *galloc = 0;
    }
    gridbar(&bars[0], NBLD);

    // ---------------- phase B: bucket + count (grid-strided, 1024 edges/vb)
    const int nvb = (E + 1023) / 1024;
    for (int vb = b; vb < nvb; vb += NBLD) {
        if (tid < 8) lpos[tid] = 0;
        __syncthreads();
        int i0 = (vb * 256 + tid) * 4;
        int part[4]; int off[4]; unsigned pk[4]; int c = 0;
        if (i0 + 3 < E) {
            int4 s4 = *(const int4*)&src[i0];
            int4 d4 = *(const int4*)&dst[i0];
            int ss[4] = {s4.x, s4.y, s4.z, s4.w};
            int dd[4] = {d4.x, d4.y, d4.z, d4.w};
            c = 4;
#pragma unroll
            for (int k = 0; k < 4; k++) {
                part[k] = min(7, (int)((float)dd[k] * p8n));
                pk[k] = ((unsigned)dd[k] << 16) | (unsigned)ss[k];
                off[k] = atomicAdd(&lpos[part[k]], 1);
                atomicAdd(&cnt[dd[k]], 1);
            }
        } else {
            for (int k = 0; k < 4 && i0 + k < E; k++) {
                int s = src[i0 + k], d = dst[i0 + k];
                part[c] = min(7, (int)((float)d * p8n));
                pk[c] = ((unsigned)d << 16) | (unsigned)s;
                off[c] = atomicAdd(&lpos[part[c]], 1);
                atomicAdd(&cnt[d], 1);
                c++;
            }
        }
        __syncthreads();
        if (tid < 8) lbase[tid] = atomicAdd(&pcnt[tid], lpos[tid]);
        __syncthreads();
        for (int k = 0; k < c; k++) {
            int idx = lbase[part[k]] + off[k];
            if (idx < ECAP) ebuf[(size_t)part[k] * ECAP + idx] = pk[k];
        }
        __syncthreads();
    }
    gridbar(&bars[1], NBLD);

    // ---------------- phase C: place (196 vblocks, direct)
    if (b < nbz) {
        int i = b * 256 + tid;
        // atomic relaxed load: bypass possibly-stale L1 (cnt was updated by
        // other XCDs' atomics in phase B)
        int c = (i < n) ? __hip_atomic_load(&cnt[i], __ATOMIC_RELAXED,
                                            __HIP_MEMORY_SCOPE_AGENT) : 0;
        int sz = (i < n) ? ((c + 8) & ~7) : 0;   // round8(deg+1)
        lds[tid] = sz;
        __syncthreads();
        for (int off = 1; off < 256; off <<= 1) {
            int x = (tid >= off) ? lds[tid - off] : 0;
            __syncthreads();
            lds[tid] += x;
            __syncthreads();
        }
        int incl = lds[tid];
        if (tid == 255) gbase = atomicAdd(galloc, incl);
        __syncthreads();
        int base = gbase + incl - sz;
        if (i < n) {
            rsp[i] = base;
            cursor[i] = base + 1;          // slot base holds the self-edge
            esrc[base] = (ushort)i;
            for (int p = base + 1 + c; p < base + sz; p++) esrc[p] = (ushort)n;
        }
    }
}

// ---------------------------------------------------------------- GEMM body
// R6-verified direct-load form (LDS-staged R9 variant was neutral). Block =
// 128 rows x 4 N-tiles; wave = 32 rows. C chunk-major pitch (n_rows+1),
// rows PRE-SCALED by rsqrt(cnt+1); nt C-stores (gather FETCH at 25MB ideal).
template <bool RELU_IN>
__device__ __forceinline__ void gemm_body(
    int bx, int by, const float* __restrict__ A,
    const ushort* __restrict__ Bthi, const ushort* __restrict__ Btlo,
    const int* __restrict__ cntp, float* __restrict__ C, int n_rows) {
    const int tid = threadIdx.x;
    const int bm0 = bx * 128;                // block covers 128 rows
    const int wv = tid >> 6;
    const int lane = tid & 63;
    const int col = lane & 15;     // A row-in-frag / B col / C col
    const int quad = lane >> 4;    // k-block for A/B; row-quad for C
    const int rbase = bm0 + wv * 32 + col;   // wave rows: rbase + m*16, m<2
    const int ntBase = by * 4;

    f32x4 acc[2][4];   // [m][nt]
#pragma unroll
    for (int m = 0; m < 2; m++)
#pragma unroll
        for (int t = 0; t < 4; t++) acc[m][t] = (f32x4){0.f, 0.f, 0.f, 0.f};

#pragma unroll
    for (int k0 = 0; k0 < 4; k0++) {
        const int kb = k0 * 32 + quad * 8;
        bf16x8 ah[2], al[2];
#pragma unroll
        for (int m = 0; m < 2; m++) {
            int arow = rbase + m * 16;
            bool av = (arow < n_rows);
            const float* __restrict__ Ap = A + (size_t)arow * CH + kb;
            float4 f0 = av ? *(const float4*)Ap       : make_float4(0.f, 0.f, 0.f, 0.f);
            float4 f1 = av ? *(const float4*)(Ap + 4) : make_float4(0.f, 0.f, 0.f, 0.f);
            if (RELU_IN) {
                f0.x = fmaxf(f0.x, 0.f); f0.y = fmaxf(f0.y, 0.f);
                f0.z = fmaxf(f0.z, 0.f); f0.w = fmaxf(f0.w, 0.f);
                f1.x = fmaxf(f1.x, 0.f); f1.y = fmaxf(f1.y, 0.f);
                f1.z = fmaxf(f1.z, 0.f); f1.w = fmaxf(f1.w, 0.f);
            }
            float fa[8] = {f0.x, f0.y, f0.z, f0.w, f1.x, f1.y, f1.z, f1.w};
#pragma unroll
            for (int j = 0; j < 8; j++) {
                ushort h = f2bf(fa[j]);
                ah[m][j] = (short)h;
                al[m][j] = (short)f2bf(fa[j] - bf2f(h));
            }
        }
#pragma unroll
        for (int t = 0; t < 4; t++) {
            const int boff = ((ntBase + t) * 16 + col) * CH + kb;
            bf16x8 bh = *(const bf16x8*)&Bthi[boff];
            bf16x8 bl = *(const bf16x8*)&Btlo[boff];
#pragma unroll
            for (int m = 0; m < 2; m++) {
                acc[m][t] = __builtin_amdgcn_mfma_f32_16x16x32_bf16(ah[m], bh, acc[m][t], 0, 0, 0);
                acc[m][t] = __builtin_amdgcn_mfma_f32_16x16x32_bf16(ah[m], bl, acc[m][t], 0, 0, 0);
                acc[m][t] = __builtin_amdgcn_mfma_f32_16x16x32_bf16(al[m], bh, acc[m][t], 0, 0, 0);
            }
        }
    }

    // epilogue: C/D layout col=lane&15, row=quad*4+reg (m89-verified)
#pragma unroll
    for (int m = 0; m < 2; m++) {
#pragma unroll
        for (int reg = 0; reg < 4; reg++) {
            int gr = bm0 + wv * 32 + m * 16 + quad * 4 + reg;
            if (gr < n_rows) {
                float d = rsqrtf((float)cntp[gr] + 1.0f);
#pragma unroll
                for (int t = 0; t < 4; t++) {
                    int nt = ntBase + t;
                    __builtin_nontemporal_store(
                        acc[m][t][reg] * d,
                        &C[((size_t)nt * (n_rows + 1) + gr) * CHK + col]);
                }
            }
        }
    }
}

// ------------------------------------------------- fused GEMM || CSR-fill
// Blocks [0, gemmBlocks): the MFMA GEMM (layer 1). Blocks [gemmBlocks,
// +2048): the bucket-fed partition-local CSR fill (independent work; nt
// C-stores keep the esrc scatter L2-resident).
template <bool RELU_IN>
__global__ __launch_bounds__(256, 4) void gemmfill_kernel(
    const float* __restrict__ A, const ushort* __restrict__ Bthi,
    const ushort* __restrict__ Btlo, const int* __restrict__ cntp,
    float* __restrict__ C, int n_rows, int nbx, int gemmBlocks,
    const unsigned* __restrict__ ebuf, const int* __restrict__ pcnt,
    int* __restrict__ cursor, ushort* __restrict__ esrc) {
    int b = blockIdx.x;
    if (b < gemmBlocks) {
        gemm_body<RELU_IN>(b % nbx, b / nbx, A, Bthi, Btlo, cntp, C, n_rows);
    } else {
        int fb = b - gemmBlocks;              // 0..2047
        int part = fb & 7;
        int m = min(pcnt[part], ECAP);
        const unsigned* bk = ebuf + (size_t)part * ECAP;
        for (int e = (fb >> 3) * 256 + (int)threadIdx.x; e < m; e += 256 * 256) {
            unsigned pe = bk[e];
            int p = atomicAdd(&cursor[pe >> 16], 1);
            esrc[p] = (ushort)(pe & 0xffffu);
        }
    }
}

// ---------------------------------------------------------------- CSR gather
// R6 body, unchanged -- at the per-CU MSHR x L2-latency floor (model: 27k
// random lines/CU at ~64 MSHR, 250cy => 44.5us = measured 45). wave = (16
// nodes, 1 chunk); chunk = blockIdx%8 pins the 3.2MB slice/XCD; sequential
// pre-warm; nt out-stores; plain cached esrc.
__global__ __launch_bounds__(256) void gather_kernel(
    const int* __restrict__ rsp, const int* __restrict__ cnt,
    const ushort* __restrict__ esrc, const float* __restrict__ hC,
    const float* __restrict__ bias, float* __restrict__ out, int n) {
    int c = blockIdx.x & 7;
    int wv = threadIdx.x >> 6;
    int lane = threadIdx.x & 63;
    int g = lane >> 2;    // node slot 0..15
    int q = lane & 3;     // float4 within the 16-channel row
    int i = (blockIdx.x >> 3) * 64 + wv * 16 + g;
    bool valid = (i < n);
    int iw = valid ? i : 0;
    const float4* __restrict__ h4 = (const float4*)(hC + (size_t)c * (n + 1) * CHK);

    // sequential L2 pre-warm: one float4 per thread covers the slice
    float warm = 0.f;
    {
        int nblk = (n + 63) >> 6;                       // blocks per chunk
        size_t p = (size_t)(blockIdx.x >> 3) * 256 + threadIdx.x;
        size_t sliceF4 = ((size_t)(n + 1) * CHK) >> 2;  // float4 count
        for (; p < sliceF4; p += (size_t)nblk * 256) {
            float4 v = h4[p];
            warm += v.x + v.y + v.z + v.w;
        }
    }

    int beg = valid ? rsp[iw] : 0;
    int cv  = valid ? cnt[iw] : -8;
    int pc  = (cv + 8) & ~7;          // round8(deg+1); 0 for invalid
    float4 acc = make_float4(0.f, 0.f, 0.f, 0.f);
    for (int j = beg; j < beg + pc; j += 8) {   // beg is a multiple of 8
        ushort4 e0 = *(const ushort4*)&esrc[j];
        ushort4 e1 = *(const ushort4*)&esrc[j + 4];
        float4 v0 = h4[(size_t)e0.x * 4 + q];
        float4 v1 = h4[(size_t)e0.y * 4 + q];
        float4 v2 = h4[(size_t)e0.z * 4 + q];
        float4 v3 = h4[(size_t)e0.w * 4 + q];
        float4 v4 = h4[(size_t)e1.x * 4 + q];
        float4 v5 = h4[(size_t)e1.y * 4 + q];
        float4 v6 = h4[(size_t)e1.z * 4 + q];
        float4 v7 = h4[(size_t)e1.w * 4 + q];
        acc.x += v0.x; acc.y += v0.y; acc.z += v0.z; acc.w += v0.w;
        acc.x += v1.x; acc.y += v1.y; acc.z += v1.z; acc.w += v1.w;
        acc.x += v2.x; acc.y += v2.y; acc.z += v2.z; acc.w += v2.w;
        acc.x += v3.x; acc.y += v3.y; acc.z += v3.z; acc.w += v3.w;
        acc.x += v4.x; acc.y += v4.y; acc.z += v4.z; acc.w += v4.w;
        acc.x += v5.x; acc.y += v5.y; acc.z += v5.z; acc.w += v5.w;
        acc.x += v6.x; acc.y += v6.y; acc.z += v6.z; acc.w += v6.w;
        acc.x += v7.x; acc.y += v7.y; acc.z += v7.z; acc.w += v7.w;
    }
    // keep the warm loads alive (cannot be DCE'd)
    __asm__ volatile("" : : "v"(warm));
    if (valid) {
        float di = rsqrtf((float)cv + 1.0f);
        float4 bv = ((const float4*)bias)[c * 4 + q];
        f32x4 o;
        o[0] = bv.x + di * acc.x;
        o[1] = bv.y + di * acc.y;
        o[2] = bv.z + di * acc.z;
        o[3] = bv.w + di * acc.w;
        __builtin_nontemporal_store(o, (f32x4*)&((float4*)out)[(size_t)iw * 32 + c * 4 + q]);
    }
}

// ---------------------------------------------------------------- head
__global__ __launch_bounds__(256) void head_kernel(
    const float* __restrict__ A, const float* __restrict__ Wh,
    const float* __restrict__ bh, float* __restrict__ out, int n) {
    __shared__ float Ws[CH * NCLS];
    __shared__ float As[16][129];
    const int tid = threadIdx.x;
    const int n0 = blockIdx.x * 16;
#pragma unroll
    for (int i = 0; i < 8; i++) {
        int l = tid + i * 256;
        Ws[l] = Wh[l];
    }
#pragma unroll
    for (int i = 0; i < 8; i++) {
        int l = tid + i * 256;
        int r = l >> 7, c = l & 127;
        int gr = n0 + r;
        As[r][c] = (gr < n) ? fmaxf(A[(size_t)gr * CH + c], 0.0f) : 0.0f;
    }
    __syncthreads();
    int r = tid >> 4, c = tid & 15;
    float acc = bh[c];
#pragma unroll
    for (int k = 0; k < CH; k++) acc = fmaf(As[r][k], Ws[k * NCLS + c], acc);
    int gr = n0 + r;
    if (gr < n) out[(size_t)gr * NCLS + c] = acc;
}

// ---------------------------------------------------------------- launch
extern "C" void kernel_launch(void* const* d_in, const int* in_sizes, int n_in,
                              void* d_out, int out_size, void* d_ws, size_t ws_size,
                              hipStream_t stream) {
    const float* x  = (const float*)d_in[0];
    const int*   ei = (const int*)d_in[1];
    const float* W1 = (const float*)d_in[2];
    const float* b1 = (const float*)d_in[3];
    const float* W2 = (const float*)d_in[4];
    const float* b2 = (const float*)d_in[5];
    const float* Wh = (const float*)d_in[6];
    const float* bh = (const float*)d_in[7];
    float* out = (float*)d_out;

    const int n = in_sizes[0] / CH;   // 50000
    const int E = in_sizes[1] / 2;    // 800000
    const int* src = ei;
    const int* dst = ei + E;

    // workspace layout (all chunks 16B aligned)
    ushort* w1hi = (ushort*)d_ws;                    // 16384 each
    ushort* w1lo = w1hi + CH * CH;
    ushort* w2hi = w1lo + CH * CH;
    ushort* w2lo = w2hi + CH * CH;
    float* bufA = (float*)(w2lo + CH * CH);          // (n+1)*128 chunk-major h'
    float* bufB = bufA + (size_t)(n + 1) * CH;       // n*128 row-major
    int* cnt    = (int*)(bufB + (size_t)n * CH);     // n  (in-degrees)
    int* rsp    = cnt + n;                           // n  (region starts)
    int* cursor = rsp + n;                           // n
    int* pcnt   = cursor + n;                        // 8
    int* galloc = pcnt + 8;                          // 1 (+7 pad)
    int* bars   = galloc + 8;                        // 4 barrier counters
    ushort* esrc = (ushort*)(bars + 8);              // <= E + 8n padded edges
    unsigned* ebuf = (unsigned*)bufB;                // 8*ECAP = 4MB, aliases
                                                     // bufB (dead till gather1)

    const int B = 256;
    const int nbz = (n + B - 1) / B;                 // place vblocks (196)
    const int nbx = (n + 127) / 128;                 // gemm x-blocks (391)
    const int gemmBlocks = nbx * 2;                  // 782
    const float p8n = 8.0f / (float)n;               // partition map scale

    // ---- build: memset barrier ctrs, then ONE persistent kernel
    //      (prep | bar | bucket+count | bar | place)
    hipMemsetAsync(bars, 0, 16, stream);
    build_kernel<<<NBLD, B, 0, stream>>>(W1, W2, w1hi, w1lo, w2hi, w2lo,
                                         src, dst, ebuf, pcnt, cnt, rsp, cursor,
                                         galloc, esrc, bufA, bars, n, E, p8n, nbz);

    const int gatherGrid = NCHUNK * ((n + 63) / 64);   // 64 nodes/block/chunk

    // layer 1 (gemm || csr-fill fused; fill hides under the GEMM)
    gemmfill_kernel<false><<<gemmBlocks + 2048, B, 0, stream>>>(
        x, w1hi, w1lo, cnt, bufA, n, nbx, gemmBlocks, ebuf, pcnt, cursor, esrc);
    gather_kernel<<<gatherGrid, B, 0, stream>>>(rsp, cnt, esrc, bufA, b1, bufB, n);
    // layer 2 (pure gemm)
    gemmfill_kernel<true><<<gemmBlocks, B, 0, stream>>>(
        bufB, w2hi, w2lo, cnt, bufA, n, nbx, gemmBlocks, ebuf, pcnt, cursor, esrc);
    gather_kernel<<<gatherGrid, B, 0, stream>>>(rsp, cnt, esrc, bufA, b2, bufB, n);
    // head
    head_kernel<<<(n + 15) / 16, B, 0, stream>>>(bufB, Wh, bh, out, n);
}

// Round 12
// 262.593 us; speedup vs baseline: 1.7096x; 1.7096x over previous
//
#include <hip/hip_runtime.h>

#define CH 128
#define NCLS 16
#define CHK 32          // channels per chunk (fp16: 32ch = 64B row)
#define NCHUNK 4        // 4 chunks of 32 == 128 channels
#define ECAP 131072     // bucket capacity per partition (E/8 = 100k expected)

typedef __attribute__((ext_vector_type(8))) short bf16x8;
typedef __attribute__((ext_vector_type(4))) float f32x4;
typedef __attribute__((ext_vector_type(8))) _Float16 f16x8;

__device__ inline ushort f2bf(float f) {        // RTNE fp32 -> bf16 bits
    unsigned u = __float_as_uint(f);
    unsigned r = u + 0x7fffu + ((u >> 16) & 1u);
    return (ushort)(r >> 16);
}
__device__ inline float bf2f(ushort b) {
    return __uint_as_float(((unsigned)b) << 16);
}
__device__ inline ushort f2h(float f) {         // RTNE fp32 -> fp16 bits
    _Float16 h = (_Float16)f;
    ushort u;
    __builtin_memcpy(&u, &h, 2);
    return u;
}

// ---------------------------------------------------------------- prep (fused)
// b<128: bf16 hi/lo weight split. Next nbz blocks: zero cnt. Last block:
// zero hC row n per chunk (pad-node target) + pcnt + galloc.
__global__ __launch_bounds__(256) void prep_kernel(
    const float* __restrict__ W1, const float* __restrict__ W2,
    ushort* __restrict__ w1hi, ushort* __restrict__ w1lo,
    ushort* __restrict__ w2hi, ushort* __restrict__ w2lo,
    int* __restrict__ cnt, int* __restrict__ pcnt, int* __restrict__ galloc,
    ushort* __restrict__ hC, int n, int nbz) {
    int b = blockIdx.x, tid = threadIdx.x;
    if (b < 128) {
        const float* W = (b < 64) ? W1 : W2;
        ushort* Whi = (b < 64) ? w1hi : w2hi;
        ushort* Wlo = (b < 64) ? w1lo : w2lo;
        int t = ((b & 63) << 8) + tid;
        int k = t >> 7, nn = t & 127;
        float v = W[t];
        ushort h = f2bf(v);
        Whi[nn * CH + k] = h;
        Wlo[nn * CH + k] = f2bf(v - bf2f(h));
    } else if (b < 128 + nbz) {
        int i = (b - 128) * 256 + tid;
        if (i < n) cnt[i] = 0;
    } else {
        if (tid < NCHUNK * CHK) {
            int c = tid >> 5, ch = tid & 31;
            hC[((size_t)c * (n + 1) + n) * CHK + ch] = 0;
        }
        if (tid < 8) pcnt[tid] = 0;
        if (tid == 8) *galloc = 0;
    }
}

// ------------------------------------------------------- bucket + count pass
// ONE pass over edges: pack (dst<<16)|src into 8 dst-partition buckets AND
// count degrees (fused -- separate count pass measured +12us serial, R5).
__global__ __launch_bounds__(256) void bucketcount_kernel(
    const int* __restrict__ src, const int* __restrict__ dst,
    unsigned* __restrict__ ebuf, int* __restrict__ pcnt,
    int* __restrict__ cnt, int E, float p8n) {
    __shared__ int lpos[8];
    __shared__ int lbase[8];
    int tid = threadIdx.x;
    if (tid < 8) lpos[tid] = 0;
    __syncthreads();
    int i0 = (blockIdx.x * 256 + tid) * 4;
    int part[4]; int off[4]; unsigned pk[4]; int c = 0;
    if (i0 + 3 < E) {
        int4 s4 = *(const int4*)&src[i0];
        int4 d4 = *(const int4*)&dst[i0];
        int ss[4] = {s4.x, s4.y, s4.z, s4.w};
        int dd[4] = {d4.x, d4.y, d4.z, d4.w};
        c = 4;
#pragma unroll
        for (int k = 0; k < 4; k++) {
            part[k] = min(7, (int)((float)dd[k] * p8n));
            pk[k] = ((unsigned)dd[k] << 16) | (unsigned)ss[k];
            off[k] = atomicAdd(&lpos[part[k]], 1);
            atomicAdd(&cnt[dd[k]], 1);
        }
    } else {
        for (int k = 0; k < 4 && i0 + k < E; k++) {
            int s = src[i0 + k], d = dst[i0 + k];
            part[c] = min(7, (int)((float)d * p8n));
            pk[c] = ((unsigned)d << 16) | (unsigned)s;
            off[c] = atomicAdd(&lpos[part[c]], 1);
            atomicAdd(&cnt[d], 1);
            c++;
        }
    }
    __syncthreads();
    if (tid < 8) lbase[tid] = atomicAdd(&pcnt[tid], lpos[tid]);
    __syncthreads();
    for (int k = 0; k < c; k++) {
        int idx = lbase[part[k]] + off[k];
        if (idx < ECAP) ebuf[(size_t)part[k] * ECAP + idx] = pk[k];
    }
}

// ---------------------------------------------------------------- place
// Dense-CSR region allocator, NO global scan: block-local LDS scan of
// round8(deg+1) + ONE global atomicAdd per block. Regions unordered across
// blocks (fine -- gather locates via rsp[i]). Writes self-edge + pads.
__global__ __launch_bounds__(256) void place_kernel(
    const int* __restrict__ cnt, int* __restrict__ rsp,
    int* __restrict__ cursor, int* __restrict__ galloc,
    ushort* __restrict__ esrc, int n) {
    __shared__ int lds[256];
    __shared__ int gbase;
    int t = threadIdx.x;
    int i = blockIdx.x * 256 + t;
    int c = (i < n) ? cnt[i] : 0;
    int sz = (i < n) ? ((c + 8) & ~7) : 0;   // round8(deg+1)
    lds[t] = sz;
    __syncthreads();
    for (int off = 1; off < 256; off <<= 1) {
        int x = (t >= off) ? lds[t - off] : 0;
        __syncthreads();
        lds[t] += x;
        __syncthreads();
    }
    int incl = lds[t];
    if (t == 255) gbase = atomicAdd(galloc, incl);
    __syncthreads();
    int base = gbase + incl - sz;
    if (i < n) {
        rsp[i] = base;
        cursor[i] = base + 1;          // slot base holds the self-edge
        esrc[base] = (ushort)i;
        for (int p = base + 1 + c; p < base + sz; p++) esrc[p] = (ushort)n;
    }
}

// ---------------------------------------------------------------- GEMM body
// C = relu?(A) @ W, bf16 hi/lo split, direct A-loads (R6-verified best).
// C is FP16 chunk-major, 4 chunks x 32ch, interleaved ch=2*col+(nt&1)
// so each (m,reg) writes 2 halves per chunk-pair as ONE packed 4B nt-store.
// fp16 h halves the gather's random-line count (8->4 lines/edge) -- the
// gather was at the MSHR x latency floor which scales with line count.
// Rows PRE-SCALED by rsqrt(cnt[row]+1).
template <bool RELU_IN>
__device__ __forceinline__ void gemm_body(
    int bx, int by, const float* __restrict__ A,
    const ushort* __restrict__ Bthi, const ushort* __restrict__ Btlo,
    const int* __restrict__ cntp, ushort* __restrict__ C16, int n_rows) {
    const int tid = threadIdx.x;
    const int bm0 = bx * 128;                // block covers 128 rows
    const int wv = tid >> 6;
    const int lane = tid & 63;
    const int col = lane & 15;     // A row-in-frag / B col / C col
    const int quad = lane >> 4;    // k-block for A/B; row-quad for C
    const int rbase = bm0 + wv * 32 + col;   // wave rows: rbase + m*16, m<2
    const int ntBase = by * 4;

    f32x4 acc[2][4];   // [m][nt]
#pragma unroll
    for (int m = 0; m < 2; m++)
#pragma unroll
        for (int t = 0; t < 4; t++) acc[m][t] = (f32x4){0.f, 0.f, 0.f, 0.f};

#pragma unroll
    for (int k0 = 0; k0 < 4; k0++) {
        const int kb = k0 * 32 + quad * 8;
        bf16x8 ah[2], al[2];
#pragma unroll
        for (int m = 0; m < 2; m++) {
            int arow = rbase + m * 16;
            bool av = (arow < n_rows);
            const float* __restrict__ Ap = A + (size_t)arow * CH + kb;
            float4 f0 = av ? *(const float4*)Ap       : make_float4(0.f, 0.f, 0.f, 0.f);
            float4 f1 = av ? *(const float4*)(Ap + 4) : make_float4(0.f, 0.f, 0.f, 0.f);
            if (RELU_IN) {
                f0.x = fmaxf(f0.x, 0.f); f0.y = fmaxf(f0.y, 0.f);
                f0.z = fmaxf(f0.z, 0.f); f0.w = fmaxf(f0.w, 0.f);
                f1.x = fmaxf(f1.x, 0.f); f1.y = fmaxf(f1.y, 0.f);
                f1.z = fmaxf(f1.z, 0.f); f1.w = fmaxf(f1.w, 0.f);
            }
            float fa[8] = {f0.x, f0.y, f0.z, f0.w, f1.x, f1.y, f1.z, f1.w};
#pragma unroll
            for (int j = 0; j < 8; j++) {
                ushort h = f2bf(fa[j]);
                ah[m][j] = (short)h;
                al[m][j] = (short)f2bf(fa[j] - bf2f(h));
            }
        }
#pragma unroll
        for (int t = 0; t < 4; t++) {
            const int boff = ((ntBase + t) * 16 + col) * CH + kb;
            bf16x8 bh = *(const bf16x8*)&Bthi[boff];
            bf16x8 bl = *(const bf16x8*)&Btlo[boff];
#pragma unroll
            for (int m = 0; m < 2; m++) {
                acc[m][t] = __builtin_amdgcn_mfma_f32_16x16x32_bf16(ah[m], bh, acc[m][t], 0, 0, 0);
                acc[m][t] = __builtin_amdgcn_mfma_f32_16x16x32_bf16(ah[m], bl, acc[m][t], 0, 0, 0);
                acc[m][t] = __builtin_amdgcn_mfma_f32_16x16x32_bf16(al[m], bh, acc[m][t], 0, 0, 0);
            }
        }
    }

    // epilogue: C/D layout col=lane&15, row=quad*4+reg (m89-verified).
    // fp16 pack: chunk = nt0>>1 (nt0 even), halves for nt0/nt0+1 at
    // ch = 2*col / 2*col+1 -> one 4B nt-store.
#pragma unroll
    for (int m = 0; m < 2; m++) {
#pragma unroll
        for (int reg = 0; reg < 4; reg++) {
            int gr = bm0 + wv * 32 + m * 16 + quad * 4 + reg;
            if (gr < n_rows) {
                float d = rsqrtf((float)cntp[gr] + 1.0f);
#pragma unroll
                for (int tp = 0; tp < 4; tp += 2) {
                    int nt0 = ntBase + tp;
                    int chunk = nt0 >> 1;
                    unsigned h0 = f2h(acc[m][tp][reg] * d);
                    unsigned h1 = f2h(acc[m][tp + 1][reg] * d);
                    unsigned pk = h0 | (h1 << 16);
                    __builtin_nontemporal_store(pk,
                        (unsigned*)&C16[((size_t)chunk * (n_rows + 1) + gr) * CHK
                                        + 2 * col]);
                }
            }
        }
    }
}

// ------------------------------------------------- fused GEMM || CSR-fill
// Blocks [0, gemmBlocks): the MFMA GEMM (layer 1). Blocks [gemmBlocks,
// +2048): the bucket-fed partition-local CSR fill (independent work; nt
// C-stores keep the esrc scatter L2-resident).
template <bool RELU_IN>
__global__ __launch_bounds__(256, 4) void gemmfill_kernel(
    const float* __restrict__ A, const ushort* __restrict__ Bthi,
    const ushort* __restrict__ Btlo, const int* __restrict__ cntp,
    ushort* __restrict__ C16, int n_rows, int nbx, int gemmBlocks,
    const unsigned* __restrict__ ebuf, const int* __restrict__ pcnt,
    int* __restrict__ cursor, ushort* __restrict__ esrc) {
    int b = blockIdx.x;
    if (b < gemmBlocks) {
        gemm_body<RELU_IN>(b % nbx, b / nbx, A, Bthi, Btlo, cntp, C16, n_rows);
    } else {
        int fb = b - gemmBlocks;              // 0..2047
        int part = fb & 7;
        int m = min(pcnt[part], ECAP);
        const unsigned* bk = ebuf + (size_t)part * ECAP;
        for (int e = (fb >> 3) * 256 + (int)threadIdx.x; e < m; e += 256 * 256) {
            unsigned pe = bk[e];
            int p = atomicAdd(&cursor[pe >> 16], 1);
            esrc[p] = (ushort)(pe & 0xffffu);
        }
    }
}

// ---------------------------------------------------------------- CSR gather
// fp16 h: 4 chunks of 32ch, 64B rows. chunk = blockIdx&3, bic = blockIdx>>2.
// wave = 16 nodes x 4 lanes; lane q reads 16B = 8 halves (interleaved
// layout -> unpack into two float4 accs). Halves the random-line count per
// edge vs fp32 (4 lines instead of 8) -- directly scales the MSHR x
// L2-latency floor the gather sits at (R9 model = 45us measured).
// Pre-warm + nt out-stores + plain cached esrc as verified.
__global__ __launch_bounds__(256) void gather_kernel(
    const int* __restrict__ rsp, const int* __restrict__ cnt,
    const ushort* __restrict__ esrc, const ushort* __restrict__ hC16,
    const float* __restrict__ bias, float* __restrict__ out, int n) {
    int c = blockIdx.x & 3;
    int bic = blockIdx.x >> 2;
    int wv = threadIdx.x >> 6;
    int lane = threadIdx.x & 63;
    int g = lane >> 2;    // node slot 0..15
    int q = lane & 3;     // 16B quarter of the 64B row
    int i = bic * 64 + wv * 16 + g;
    bool valid = (i < n);
    int iw = valid ? i : 0;
    const f16x8* __restrict__ h8 = (const f16x8*)(hC16 + (size_t)c * (n + 1) * CHK);

    // sequential L2 pre-warm: one float4 per thread covers the 3.2MB slice
    float warm = 0.f;
    {
        int nbr = (n + 63) >> 6;                        // blocks per chunk
        const float4* __restrict__ w4 = (const float4*)h8;
        size_t p = (size_t)bic * 256 + threadIdx.x;
        size_t sliceF4 = ((size_t)(n + 1) * CHK) >> 3;  // 2B elems /8 = float4
        for (; p < sliceF4; p += (size_t)nbr * 256) {
            float4 v = w4[p];
            warm += v.x + v.y + v.z + v.w;
        }
    }

    int beg = valid ? rsp[iw] : 0;
    int cv  = valid ? cnt[iw] : -8;
    int pc  = (cv + 8) & ~7;          // round8(deg+1); 0 for invalid
    float accA[4] = {0.f, 0.f, 0.f, 0.f};
    float accB[4] = {0.f, 0.f, 0.f, 0.f};
    for (int j = beg; j < beg + pc; j += 8) {   // beg is a multiple of 8
        ushort4 e0 = *(const ushort4*)&esrc[j];
        ushort4 e1 = *(const ushort4*)&esrc[j + 4];
        f16x8 v0 = h8[(size_t)e0.x * 4 + q];
        f16x8 v1 = h8[(size_t)e0.y * 4 + q];
        f16x8 v2 = h8[(size_t)e0.z * 4 + q];
        f16x8 v3 = h8[(size_t)e0.w * 4 + q];
        f16x8 v4 = h8[(size_t)e1.x * 4 + q];
        f16x8 v5 = h8[(size_t)e1.y * 4 + q];
        f16x8 v6 = h8[(size_t)e1.z * 4 + q];
        f16x8 v7 = h8[(size_t)e1.w * 4 + q];
#pragma unroll
        for (int s = 0; s < 4; s++) {
            accA[s] += (float)v0[2 * s]; accB[s] += (float)v0[2 * s + 1];
            accA[s] += (float)v1[2 * s]; accB[s] += (float)v1[2 * s + 1];
            accA[s] += (float)v2[2 * s]; accB[s] += (float)v2[2 * s + 1];
            accA[s] += (float)v3[2 * s]; accB[s] += (float)v3[2 * s + 1];
            accA[s] += (float)v4[2 * s]; accB[s] += (float)v4[2 * s + 1];
            accA[s] += (float)v5[2 * s]; accB[s] += (float)v5[2 * s + 1];
            accA[s] += (float)v6[2 * s]; accB[s] += (float)v6[2 * s + 1];
            accA[s] += (float)v7[2 * s]; accB[s] += (float)v7[2 * s + 1];
        }
    }
    // keep the warm loads alive (cannot be DCE'd)
    __asm__ volatile("" : : "v"(warm));
    if (valid) {
        // lane q's halves: even ch -> true channels 32c+4q+s, odd ->
        // 32c+16+4q+s (s=0..3): two float4 groups, row-major out.
        float di = rsqrtf((float)cv + 1.0f);
        const float4* bias4 = (const float4*)bias;
        float4 bvA = bias4[8 * c + q];
        float4 bvB = bias4[8 * c + 4 + q];
        f32x4 oA, oB;
        oA[0] = bvA.x + di * accA[0]; oA[1] = bvA.y + di * accA[1];
        oA[2] = bvA.z + di * accA[2]; oA[3] = bvA.w + di * accA[3];
        oB[0] = bvB.x + di * accB[0]; oB[1] = bvB.y + di * accB[1];
        oB[2] = bvB.z + di * accB[2]; oB[3] = bvB.w + di * accB[3];
        float4* out4 = (float4*)out;
        __builtin_nontemporal_store(oA, (f32x4*)&out4[(size_t)iw * 32 + 8 * c + q]);
        __builtin_nontemporal_store(oB, (f32x4*)&out4[(size_t)iw * 32 + 8 * c + 4 + q]);
    }
}

// ---------------------------------------------------------------- head
__global__ __launch_bounds__(256) void head_kernel(
    const float* __restrict__ A, const float* __restrict__ Wh,
    const float* __restrict__ bh, float* __restrict__ out, int n) {
    __shared__ float Ws[CH * NCLS];
    __shared__ float As[16][129];
    const int tid = threadIdx.x;
    const int n0 = blockIdx.x * 16;
#pragma unroll
    for (int i = 0; i < 8; i++) {
        int l = tid + i * 256;
        Ws[l] = Wh[l];
    }
#pragma unroll
    for (int i = 0; i < 8; i++) {
        int l = tid + i * 256;
        int r = l >> 7, c = l & 127;
        int gr = n0 + r;
        As[r][c] = (gr < n) ? fmaxf(A[(size_t)gr * CH + c], 0.0f) : 0.0f;
    }
    __syncthreads();
    int r = tid >> 4, c = tid & 15;
    float acc = bh[c];
#pragma unroll
    for (int k = 0; k < CH; k++) acc = fmaf(As[r][k], Ws[k * NCLS + c], acc);
    int gr = n0 + r;
    if (gr < n) out[(size_t)gr * NCLS + c] = acc;
}

// ---------------------------------------------------------------- launch
extern "C" void kernel_launch(void* const* d_in, const int* in_sizes, int n_in,
                              void* d_out, int out_size, void* d_ws, size_t ws_size,
                              hipStream_t stream) {
    const float* x  = (const float*)d_in[0];
    const int*   ei = (const int*)d_in[1];
    const float* W1 = (const float*)d_in[2];
    const float* b1 = (const float*)d_in[3];
    const float* W2 = (const float*)d_in[4];
    const float* b2 = (const float*)d_in[5];
    const float* Wh = (const float*)d_in[6];
    const float* bh = (const float*)d_in[7];
    float* out = (float*)d_out;

    const int n = in_sizes[0] / CH;   // 50000
    const int E = in_sizes[1] / 2;    // 800000
    const int* src = ei;
    const int* dst = ei + E;

    // workspace layout (all chunks 16B aligned)
    ushort* w1hi = (ushort*)d_ws;                    // 16384 each
    ushort* w1lo = w1hi + CH * CH;
    ushort* w2hi = w1lo + CH * CH;
    ushort* w2lo = w2hi + CH * CH;
    ushort* hA  = w2lo + CH * CH;                    // fp16 (n+1)*128 chunk-major
    float* bufB = (float*)(hA + (size_t)(n + 1) * CH);  // n*128 row-major fp32
    int* cnt    = (int*)(bufB + (size_t)n * CH);     // n  (in-degrees)
    int* rsp    = cnt + n;                           // n  (region starts)
    int* cursor = rsp + n;                           // n
    int* pcnt   = cursor + n;                        // 8
    int* galloc = pcnt + 8;                          // 1 (+7 pad)
    ushort* esrc = (ushort*)(pcnt + 16);             // <= E + 8n padded edges
    unsigned* ebuf = (unsigned*)bufB;                // 8*ECAP = 4MB, aliases
                                                     // bufB (dead till gather1)

    const int B = 256;
    const int nbz = (n + B - 1) / B;                 // cnt-zero / place blocks
    const int nbx = (n + 127) / 128;                 // gemm x-blocks (391)
    const int gemmBlocks = nbx * 2;                  // 782
    const int nbr = (n + 63) / 64;                   // 782 node ranges
    const int gatherGrid = NCHUNK * nbr;             // 3128
    const float p8n = 8.0f / (float)n;               // partition map scale

    // ---- build: bucket+count (1 edge pass) -> place (block allocator)
    prep_kernel<<<128 + nbz + 1, B, 0, stream>>>(W1, W2, w1hi, w1lo, w2hi, w2lo,
                                                 cnt, pcnt, galloc, hA, n, nbz);
    bucketcount_kernel<<<(E + 1023) / 1024, B, 0, stream>>>(src, dst, ebuf, pcnt,
                                                            cnt, E, p8n);
    place_kernel<<<nbz, B, 0, stream>>>(cnt, rsp, cursor, galloc, esrc, n);

    // layer 1 (gemm || csr-fill fused; fill hides under the GEMM)
    gemmfill_kernel<false><<<gemmBlocks + 2048, B, 0, stream>>>(
        x, w1hi, w1lo, cnt, hA, n, nbx, gemmBlocks, ebuf, pcnt, cursor, esrc);
    gather_kernel<<<gatherGrid, B, 0, stream>>>(rsp, cnt, esrc, hA, b1, bufB, n);
    // layer 2 (pure gemm)
    gemmfill_kernel<true><<<gemmBlocks, B, 0, stream>>>(
        bufB, w2hi, w2lo, cnt, hA, n, nbx, gemmBlocks, ebuf, pcnt, cursor, esrc);
    gather_kernel<<<gatherGrid, B, 0, stream>>>(rsp, cnt, esrc, hA, b2, bufB, n);
    // head
    head_kernel<<<(n + 15) / 16, B, 0, stream>>>(bufB, Wh, bh, out, n);
}

// Round 13
// 254.128 us; speedup vs baseline: 1.7665x; 1.0333x over previous
//
#include <hip/hip_runtime.h>

#define CH 128
#define NCLS 16
#define CHK 32          // channels per chunk (fp16: 32ch = 64B row)
#define NCHUNK 4        // 4 chunks of 32 == 128 channels
#define ECAP 131072     // bucket capacity per partition (E/8 = 100k expected)

typedef __attribute__((ext_vector_type(8))) short bf16x8;
typedef __attribute__((ext_vector_type(4))) float f32x4;
typedef __attribute__((ext_vector_type(8))) _Float16 f16x8;
typedef __attribute__((ext_vector_type(4))) ushort u16x4;

__device__ inline ushort f2bf(float f) {        // RTNE fp32 -> bf16 bits
    unsigned u = __float_as_uint(f);
    unsigned r = u + 0x7fffu + ((u >> 16) & 1u);
    return (ushort)(r >> 16);
}
__device__ inline float bf2f(ushort b) {
    return __uint_as_float(((unsigned)b) << 16);
}
__device__ inline ushort f2h(float f) {         // RTNE fp32 -> fp16 bits
    _Float16 h = (_Float16)f;
    ushort u;
    __builtin_memcpy(&u, &h, 2);
    return u;
}
__device__ inline float h2f(ushort u) {
    _Float16 h;
    __builtin_memcpy(&h, &u, 2);
    return (float)h;
}

// ---------------------------------------------------------------- prep (fused)
// b<64: W1 bf16 hi/lo (layer-1 A is fp32 -> bf16 path). b in [64,128): W2
// fp16 hi/lo (layer-2 A is exact fp16 -> f16 MFMA, 11+11 mantissa bits).
// Next nbz blocks: zero cnt. Last block: zero hC row n per chunk + pcnt +
// galloc.
__global__ __launch_bounds__(256) void prep_kernel(
    const float* __restrict__ W1, const float* __restrict__ W2,
    ushort* __restrict__ w1hi, ushort* __restrict__ w1lo,
    ushort* __restrict__ w2hf, ushort* __restrict__ w2lf,
    int* __restrict__ cnt, int* __restrict__ pcnt, int* __restrict__ galloc,
    ushort* __restrict__ hC, int n, int nbz) {
    int b = blockIdx.x, tid = threadIdx.x;
    if (b < 64) {
        int t = (b << 8) + tid;
        int k = t >> 7, nn = t & 127;
        float v = W1[t];
        ushort h = f2bf(v);
        w1hi[nn * CH + k] = h;
        w1lo[nn * CH + k] = f2bf(v - bf2f(h));
    } else if (b < 128) {
        int t = ((b - 64) << 8) + tid;
        int k = t >> 7, nn = t & 127;
        float v = W2[t];
        ushort h = f2h(v);
        w2hf[nn * CH + k] = h;
        w2lf[nn * CH + k] = f2h(v - h2f(h));
    } else if (b < 128 + nbz) {
        int i = (b - 128) * 256 + tid;
        if (i < n) cnt[i] = 0;
    } else {
        if (tid < NCHUNK * CHK) {
            int c = tid >> 5, ch = tid & 31;
            hC[((size_t)c * (n + 1) + n) * CHK + ch] = 0;
        }
        if (tid < 8) pcnt[tid] = 0;
        if (tid == 8) *galloc = 0;
    }
}

// ------------------------------------------------------- bucket + count pass
// ONE pass over edges: pack (dst<<16)|src into 8 dst-partition buckets AND
// count degrees (fused -- separate count pass measured +12us serial, R5).
__global__ __launch_bounds__(256) void bucketcount_kernel(
    const int* __restrict__ src, const int* __restrict__ dst,
    unsigned* __restrict__ ebuf, int* __restrict__ pcnt,
    int* __restrict__ cnt, int E, float p8n) {
    __shared__ int lpos[8];
    __shared__ int lbase[8];
    int tid = threadIdx.x;
    if (tid < 8) lpos[tid] = 0;
    __syncthreads();
    int i0 = (blockIdx.x * 256 + tid) * 4;
    int part[4]; int off[4]; unsigned pk[4]; int c = 0;
    if (i0 + 3 < E) {
        int4 s4 = *(const int4*)&src[i0];
        int4 d4 = *(const int4*)&dst[i0];
        int ss[4] = {s4.x, s4.y, s4.z, s4.w};
        int dd[4] = {d4.x, d4.y, d4.z, d4.w};
        c = 4;
#pragma unroll
        for (int k = 0; k < 4; k++) {
            part[k] = min(7, (int)((float)dd[k] * p8n));
            pk[k] = ((unsigned)dd[k] << 16) | (unsigned)ss[k];
            off[k] = atomicAdd(&lpos[part[k]], 1);
            atomicAdd(&cnt[dd[k]], 1);
        }
    } else {
        for (int k = 0; k < 4 && i0 + k < E; k++) {
            int s = src[i0 + k], d = dst[i0 + k];
            part[c] = min(7, (int)((float)d * p8n));
            pk[c] = ((unsigned)d << 16) | (unsigned)s;
            off[c] = atomicAdd(&lpos[part[c]], 1);
            atomicAdd(&cnt[d], 1);
            c++;
        }
    }
    __syncthreads();
    if (tid < 8) lbase[tid] = atomicAdd(&pcnt[tid], lpos[tid]);
    __syncthreads();
    for (int k = 0; k < c; k++) {
        int idx = lbase[part[k]] + off[k];
        if (idx < ECAP) ebuf[(size_t)part[k] * ECAP + idx] = pk[k];
    }
}

// ---------------------------------------------------------------- place
// Dense-CSR region allocator, NO global scan: block-local LDS scan of
// round8(deg+1) + ONE global atomicAdd per block. Regions unordered across
// blocks (fine -- gather locates via rsp[i]). Writes self-edge + pads.
__global__ __launch_bounds__(256) void place_kernel(
    const int* __restrict__ cnt, int* __restrict__ rsp,
    int* __restrict__ cursor, int* __restrict__ galloc,
    ushort* __restrict__ esrc, int n) {
    __shared__ int lds[256];
    __shared__ int gbase;
    int t = threadIdx.x;
    int i = blockIdx.x * 256 + t;
    int c = (i < n) ? cnt[i] : 0;
    int sz = (i < n) ? ((c + 8) & ~7) : 0;   // round8(deg+1)
    lds[t] = sz;
    __syncthreads();
    for (int off = 1; off < 256; off <<= 1) {
        int x = (t >= off) ? lds[t - off] : 0;
        __syncthreads();
        lds[t] += x;
        __syncthreads();
    }
    int incl = lds[t];
    if (t == 255) gbase = atomicAdd(galloc, incl);
    __syncthreads();
    int base = gbase + incl - sz;
    if (i < n) {
        rsp[i] = base;
        cursor[i] = base + 1;          // slot base holds the self-edge
        esrc[base] = (ushort)i;
        for (int p = base + 1 + c; p < base + sz; p++) esrc[p] = (ushort)n;
    }
}

// ---------------------------------------------------------------- GEMM1 body
// hA = x @ W1 (pre-scaled), bf16 hi/lo split on fp32 A (direct loads,
// R6-verified). C is FP16 chunk-major (4 chunks x 32ch, interleaved
// ch=2*col+(nt&1)) -- one packed 4B nt-store per (m,reg,chunk).
__device__ __forceinline__ void gemm1_body(
    int bx, int by, const float* __restrict__ A,
    const ushort* __restrict__ Bthi, const ushort* __restrict__ Btlo,
    const int* __restrict__ cntp, ushort* __restrict__ C16, int n_rows) {
    const int tid = threadIdx.x;
    const int bm0 = bx * 128;                // block covers 128 rows
    const int wv = tid >> 6;
    const int lane = tid & 63;
    const int col = lane & 15;     // A row-in-frag / B col / C col
    const int quad = lane >> 4;    // k-block for A/B; row-quad for C
    const int rbase = bm0 + wv * 32 + col;   // wave rows: rbase + m*16, m<2
    const int ntBase = by * 4;

    f32x4 acc[2][4];   // [m][nt]
#pragma unroll
    for (int m = 0; m < 2; m++)
#pragma unroll
        for (int t = 0; t < 4; t++) acc[m][t] = (f32x4){0.f, 0.f, 0.f, 0.f};

#pragma unroll
    for (int k0 = 0; k0 < 4; k0++) {
        const int kb = k0 * 32 + quad * 8;
        bf16x8 ah[2], al[2];
#pragma unroll
        for (int m = 0; m < 2; m++) {
            int arow = rbase + m * 16;
            bool av = (arow < n_rows);
            const float* __restrict__ Ap = A + (size_t)arow * CH + kb;
            float4 f0 = av ? *(const float4*)Ap       : make_float4(0.f, 0.f, 0.f, 0.f);
            float4 f1 = av ? *(const float4*)(Ap + 4) : make_float4(0.f, 0.f, 0.f, 0.f);
            float fa[8] = {f0.x, f0.y, f0.z, f0.w, f1.x, f1.y, f1.z, f1.w};
#pragma unroll
            for (int j = 0; j < 8; j++) {
                ushort h = f2bf(fa[j]);
                ah[m][j] = (short)h;
                al[m][j] = (short)f2bf(fa[j] - bf2f(h));
            }
        }
#pragma unroll
        for (int t = 0; t < 4; t++) {
            const int boff = ((ntBase + t) * 16 + col) * CH + kb;
            bf16x8 bh = *(const bf16x8*)&Bthi[boff];
            bf16x8 bl = *(const bf16x8*)&Btlo[boff];
#pragma unroll
            for (int m = 0; m < 2; m++) {
                acc[m][t] = __builtin_amdgcn_mfma_f32_16x16x32_bf16(ah[m], bh, acc[m][t], 0, 0, 0);
                acc[m][t] = __builtin_amdgcn_mfma_f32_16x16x32_bf16(ah[m], bl, acc[m][t], 0, 0, 0);
                acc[m][t] = __builtin_amdgcn_mfma_f32_16x16x32_bf16(al[m], bh, acc[m][t], 0, 0, 0);
            }
        }
    }

    // epilogue: C/D layout col=lane&15, row=quad*4+reg (m89-verified)
#pragma unroll
    for (int m = 0; m < 2; m++) {
#pragma unroll
        for (int reg = 0; reg < 4; reg++) {
            int gr = bm0 + wv * 32 + m * 16 + quad * 4 + reg;
            if (gr < n_rows) {
                float d = rsqrtf((float)cntp[gr] + 1.0f);
#pragma unroll
                for (int tp = 0; tp < 4; tp += 2) {
                    int nt0 = ntBase + tp;
                    int chunk = nt0 >> 1;
                    unsigned h0 = f2h(acc[m][tp][reg] * d);
                    unsigned h1 = f2h(acc[m][tp + 1][reg] * d);
                    unsigned pk = h0 | (h1 << 16);
                    __builtin_nontemporal_store(pk,
                        (unsigned*)&C16[((size_t)chunk * (n_rows + 1) + gr) * CHK
                                        + 2 * col]);
                }
            }
        }
    }
}

// ------------------------------------------------- fused GEMM1 || CSR-fill
// Blocks [0, gemmBlocks): GEMM layer 1. Blocks [gemmBlocks, +2048): the
// bucket-fed partition-local CSR fill (independent work; nt C-stores keep
// the esrc scatter L2-resident).
__global__ __launch_bounds__(256, 4) void gemmfill_kernel(
    const float* __restrict__ A, const ushort* __restrict__ Bthi,
    const ushort* __restrict__ Btlo, const int* __restrict__ cntp,
    ushort* __restrict__ C16, int n_rows, int nbx, int gemmBlocks,
    const unsigned* __restrict__ ebuf, const int* __restrict__ pcnt,
    int* __restrict__ cursor, ushort* __restrict__ esrc) {
    int b = blockIdx.x;
    if (b < gemmBlocks) {
        gemm1_body(b % nbx, b / nbx, A, Bthi, Btlo, cntp, C16, n_rows);
    } else {
        int fb = b - gemmBlocks;              // 0..2047
        int part = fb & 7;
        int m = min(pcnt[part], ECAP);
        const unsigned* bk = ebuf + (size_t)part * ECAP;
        for (int e = (fb >> 3) * 256 + (int)threadIdx.x; e < m; e += 256 * 256) {
            unsigned pe = bk[e];
            int p = atomicAdd(&cursor[pe >> 16], 1);
            esrc[p] = (ushort)(pe & 0xffffu);
        }
    }
}

// ---------------------------------------------------------------- GEMM2
// hA = relu'd-bufB(fp16) @ W2 (pre-scaled). A is EXACT fp16 -> direct f16x8
// fragment loads, NO convert chain; W2 fp16 hi/lo -> 2 MFMAs per fragment
// pair (vs 3 bf16) with 22 effective mantissa bits on weights. A-reads
// halve (12.8MB); relu already applied at gather1's store.
__global__ __launch_bounds__(256, 4) void gemm2_kernel(
    const ushort* __restrict__ A16, const ushort* __restrict__ Bhf,
    const ushort* __restrict__ Blf, const int* __restrict__ cntp,
    ushort* __restrict__ C16, int n_rows) {
    const int tid = threadIdx.x;
    const int bm0 = blockIdx.x * 128;
    const int wv = tid >> 6;
    const int lane = tid & 63;
    const int col = lane & 15;
    const int quad = lane >> 4;
    const int rbase = bm0 + wv * 32 + col;
    const int ntBase = blockIdx.y * 4;
    const f16x8 fz = {0, 0, 0, 0, 0, 0, 0, 0};

    f32x4 acc[2][4];
#pragma unroll
    for (int m = 0; m < 2; m++)
#pragma unroll
        for (int t = 0; t < 4; t++) acc[m][t] = (f32x4){0.f, 0.f, 0.f, 0.f};

#pragma unroll
    for (int k0 = 0; k0 < 4; k0++) {
        const int kb = k0 * 32 + quad * 8;
        f16x8 a[2];
#pragma unroll
        for (int m = 0; m < 2; m++) {
            int arow = rbase + m * 16;
            a[m] = (arow < n_rows)
                 ? *(const f16x8*)(A16 + (size_t)arow * CH + kb) : fz;
        }
#pragma unroll
        for (int t = 0; t < 4; t++) {
            const int boff = ((ntBase + t) * 16 + col) * CH + kb;
            f16x8 bh = *(const f16x8*)&Bhf[boff];
            f16x8 bl = *(const f16x8*)&Blf[boff];
#pragma unroll
            for (int m = 0; m < 2; m++) {
                acc[m][t] = __builtin_amdgcn_mfma_f32_16x16x32_f16(a[m], bh, acc[m][t], 0, 0, 0);
                acc[m][t] = __builtin_amdgcn_mfma_f32_16x16x32_f16(a[m], bl, acc[m][t], 0, 0, 0);
            }
        }
    }

#pragma unroll
    for (int m = 0; m < 2; m++) {
#pragma unroll
        for (int reg = 0; reg < 4; reg++) {
            int gr = bm0 + wv * 32 + m * 16 + quad * 4 + reg;
            if (gr < n_rows) {
                float d = rsqrtf((float)cntp[gr] + 1.0f);
#pragma unroll
                for (int tp = 0; tp < 4; tp += 2) {
                    int nt0 = ntBase + tp;
                    int chunk = nt0 >> 1;
                    unsigned h0 = f2h(acc[m][tp][reg] * d);
                    unsigned h1 = f2h(acc[m][tp + 1][reg] * d);
                    unsigned pk = h0 | (h1 << 16);
                    __builtin_nontemporal_store(pk,
                        (unsigned*)&C16[((size_t)chunk * (n_rows + 1) + gr) * CHK
                                        + 2 * col]);
                }
            }
        }
    }
}

// ---------------------------------------------------------------- CSR gather
// fp16 h: 4 chunks of 32ch, 64B rows; halves the random-line count per edge
// (R12-verified: gathers dropped below the 43us harness cutoff). Output is
// FP16 row-major with RELU APPLIED AT STORE (head's fmax is idempotent;
// gemm2 needs relu'd input) -- out-stores halve to two 8B nt-stores.
__global__ __launch_bounds__(256) void gather_kernel(
    const int* __restrict__ rsp, const int* __restrict__ cnt,
    const ushort* __restrict__ esrc, const ushort* __restrict__ hC16,
    const float* __restrict__ bias, ushort* __restrict__ out16, int n) {
    int c = blockIdx.x & 3;
    int bic = blockIdx.x >> 2;
    int wv = threadIdx.x >> 6;
    int lane = threadIdx.x & 63;
    int g = lane >> 2;    // node slot 0..15
    int q = lane & 3;     // 16B quarter of the 64B row
    int i = bic * 64 + wv * 16 + g;
    bool valid = (i < n);
    int iw = valid ? i : 0;
    const f16x8* __restrict__ h8 = (const f16x8*)(hC16 + (size_t)c * (n + 1) * CHK);

    // sequential L2 pre-warm: one float4 per thread covers the 3.2MB slice
    float warm = 0.f;
    {
        int nbr = (n + 63) >> 6;                        // blocks per chunk
        const float4* __restrict__ w4 = (const float4*)h8;
        size_t p = (size_t)bic * 256 + threadIdx.x;
        size_t sliceF4 = ((size_t)(n + 1) * CHK) >> 3;  // 2B elems /8 = float4
        for (; p < sliceF4; p += (size_t)nbr * 256) {
            float4 v = w4[p];
            warm += v.x + v.y + v.z + v.w;
        }
    }

    int beg = valid ? rsp[iw] : 0;
    int cv  = valid ? cnt[iw] : -8;
    int pc  = (cv + 8) & ~7;          // round8(deg+1); 0 for invalid
    float accA[4] = {0.f, 0.f, 0.f, 0.f};
    float accB[4] = {0.f, 0.f, 0.f, 0.f};
    for (int j = beg; j < beg + pc; j += 8) {   // beg is a multiple of 8
        ushort4 e0 = *(const ushort4*)&esrc[j];
        ushort4 e1 = *(const ushort4*)&esrc[j + 4];
        f16x8 v0 = h8[(size_t)e0.x * 4 + q];
        f16x8 v1 = h8[(size_t)e0.y * 4 + q];
        f16x8 v2 = h8[(size_t)e0.z * 4 + q];
        f16x8 v3 = h8[(size_t)e0.w * 4 + q];
        f16x8 v4 = h8[(size_t)e1.x * 4 + q];
        f16x8 v5 = h8[(size_t)e1.y * 4 + q];
        f16x8 v6 = h8[(size_t)e1.z * 4 + q];
        f16x8 v7 = h8[(size_t)e1.w * 4 + q];
#pragma unroll
        for (int s = 0; s < 4; s++) {
            accA[s] += (float)v0[2 * s]; accB[s] += (float)v0[2 * s + 1];
            accA[s] += (float)v1[2 * s]; accB[s] += (float)v1[2 * s + 1];
            accA[s] += (float)v2[2 * s]; accB[s] += (float)v2[2 * s + 1];
            accA[s] += (float)v3[2 * s]; accB[s] += (float)v3[2 * s + 1];
            accA[s] += (float)v4[2 * s]; accB[s] += (float)v4[2 * s + 1];
            accA[s] += (float)v5[2 * s]; accB[s] += (float)v5[2 * s + 1];
            accA[s] += (float)v6[2 * s]; accB[s] += (float)v6[2 * s + 1];
            accA[s] += (float)v7[2 * s]; accB[s] += (float)v7[2 * s + 1];
        }
    }
    // keep the warm loads alive (cannot be DCE'd)
    __asm__ volatile("" : : "v"(warm));
    if (valid) {
        // lane q's halves: even ch -> 32c+4q+s, odd -> 32c+16+4q+s (s=0..3)
        float di = rsqrtf((float)cv + 1.0f);
        const float4* bias4 = (const float4*)bias;
        float4 bvA = bias4[8 * c + q];
        float4 bvB = bias4[8 * c + 4 + q];
        u16x4 pA, pB;
        pA[0] = f2h(fmaxf(bvA.x + di * accA[0], 0.f));
        pA[1] = f2h(fmaxf(bvA.y + di * accA[1], 0.f));
        pA[2] = f2h(fmaxf(bvA.z + di * accA[2], 0.f));
        pA[3] = f2h(fmaxf(bvA.w + di * accA[3], 0.f));
        pB[0] = f2h(fmaxf(bvB.x + di * accB[0], 0.f));
        pB[1] = f2h(fmaxf(bvB.y + di * accB[1], 0.f));
        pB[2] = f2h(fmaxf(bvB.z + di * accB[2], 0.f));
        pB[3] = f2h(fmaxf(bvB.w + di * accB[3], 0.f));
        ushort* o16 = out16 + (size_t)iw * CH + 32 * c + 4 * q;
        __builtin_nontemporal_store(pA, (u16x4*)o16);
        __builtin_nontemporal_store(pB, (u16x4*)(o16 + 16));
    }
}

// ---------------------------------------------------------------- head
// out = relu(bufB) @ Wh + bh. bufB is fp16 (already relu'd; fmax kept --
// idempotent). One f16x8 load per thread fills the 16x128 LDS tile.
__global__ __launch_bounds__(256) void head_kernel(
    const ushort* __restrict__ A16, const float* __restrict__ Wh,
    const float* __restrict__ bh, float* __restrict__ out, int n) {
    __shared__ float Ws[CH * NCLS];
    __shared__ float As[16][129];
    const int tid = threadIdx.x;
    const int n0 = blockIdx.x * 16;
#pragma unroll
    for (int i = 0; i < 8; i++) {
        int l = tid + i * 256;
        Ws[l] = Wh[l];
    }
    {
        int row = tid >> 4, c0 = (tid & 15) * 8;
        int gr = n0 + row;
        const f16x8 fz = {0, 0, 0, 0, 0, 0, 0, 0};
        f16x8 v = (gr < n) ? *(const f16x8*)(A16 + (size_t)gr * CH + c0) : fz;
#pragma unroll
        for (int j = 0; j < 8; j++) As[row][c0 + j] = fmaxf((float)v[j], 0.0f);
    }
    __syncthreads();
    int r = tid >> 4, c = tid & 15;
    float acc = bh[c];
#pragma unroll
    for (int k = 0; k < CH; k++) acc = fmaf(As[r][k], Ws[k * NCLS + c], acc);
    int gr = n0 + r;
    if (gr < n) out[(size_t)gr * NCLS + c] = acc;
}

// ---------------------------------------------------------------- launch
extern "C" void kernel_launch(void* const* d_in, const int* in_sizes, int n_in,
                              void* d_out, int out_size, void* d_ws, size_t ws_size,
                              hipStream_t stream) {
    const float* x  = (const float*)d_in[0];
    const int*   ei = (const int*)d_in[1];
    const float* W1 = (const float*)d_in[2];
    const float* b1 = (const float*)d_in[3];
    const float* W2 = (const float*)d_in[4];
    const float* b2 = (const float*)d_in[5];
    const float* Wh = (const float*)d_in[6];
    const float* bh = (const float*)d_in[7];
    float* out = (float*)d_out;

    const int n = in_sizes[0] / CH;   // 50000
    const int E = in_sizes[1] / 2;    // 800000
    const int* src = ei;
    const int* dst = ei + E;

    // workspace layout (all chunks 16B aligned)
    ushort* w1hi = (ushort*)d_ws;                    // 16384 each
    ushort* w1lo = w1hi + CH * CH;
    ushort* w2hf = w1lo + CH * CH;                   // fp16 hi
    ushort* w2lf = w2hf + CH * CH;                   // fp16 lo
    ushort* hA   = w2lf + CH * CH;                   // fp16 (n+1)*128 chunk-major
    ushort* bufB = hA + (size_t)(n + 1) * CH;        // fp16 n*128 row-major
    int* cnt    = (int*)(bufB + (size_t)n * CH);     // n  (in-degrees)
    int* rsp    = cnt + n;                           // n  (region starts)
    int* cursor = rsp + n;                           // n
    int* pcnt   = cursor + n;                        // 8
    int* galloc = pcnt + 8;                          // 1 (+7 pad)
    ushort* esrc = (ushort*)(pcnt + 16);             // <= E + 8n padded edges
    unsigned* ebuf = (unsigned*)bufB;                // 8*ECAP = 4MB, aliases
                                                     // bufB (dead till gather1)

    const int B = 256;
    const int nbz = (n + B - 1) / B;                 // cnt-zero / place blocks
    const int nbx = (n + 127) / 128;                 // gemm x-blocks (391)
    const int gemmBlocks = nbx * 2;                  // 782
    const int nbr = (n + 63) / 64;                   // 782 node ranges
    const int gatherGrid = NCHUNK * nbr;             // 3128
    const float p8n = 8.0f / (float)n;               // partition map scale

    // ---- build: bucket+count (1 edge pass) -> place (block allocator)
    prep_kernel<<<128 + nbz + 1, B, 0, stream>>>(W1, W2, w1hi, w1lo, w2hf, w2lf,
                                                 cnt, pcnt, galloc, hA, n, nbz);
    bucketcount_kernel<<<(E + 1023) / 1024, B, 0, stream>>>(src, dst, ebuf, pcnt,
                                                            cnt, E, p8n);
    place_kernel<<<nbz, B, 0, stream>>>(cnt, rsp, cursor, galloc, esrc, n);

    // layer 1 (gemm || csr-fill fused; fill hides under the GEMM)
    gemmfill_kernel<<<gemmBlocks + 2048, B, 0, stream>>>(
        x, w1hi, w1lo, cnt, hA, n, nbx, gemmBlocks, ebuf, pcnt, cursor, esrc);
    gather_kernel<<<gatherGrid, B, 0, stream>>>(rsp, cnt, esrc, hA, b1, bufB, n);
    // layer 2 (native f16 MFMA, fp16 A direct loads)
    gemm2_kernel<<<dim3(nbx, 2), B, 0, stream>>>(bufB, w2hf, w2lf, cnt, hA, n);
    gather_kernel<<<gatherGrid, B, 0, stream>>>(rsp, cnt, esrc, hA, b2, bufB, n);
    // head
    head_kernel<<<(n + 15) / 16, B, 0, stream>>>(bufB, Wh, bh, out, n);
}

// Round 14
// 239.507 us; speedup vs baseline: 1.8744x; 1.0610x over previous
//
#include <hip/hip_runtime.h>

#define CH 128
#define NCLS 16
#define CHK 32          // channels per chunk (fp16: 32ch = 64B row)
#define NCHUNK 4        // 4 chunks of 32 == 128 channels
#define ECAP 131072     // bucket capacity per partition (E/8 = 100k expected)

typedef __attribute__((ext_vector_type(8))) short bf16x8;
typedef __attribute__((ext_vector_type(4))) float f32x4;
typedef __attribute__((ext_vector_type(8))) _Float16 f16x8;
typedef __attribute__((ext_vector_type(4))) ushort u16x4;

__device__ inline ushort f2bf(float f) {        // RTNE fp32 -> bf16 bits
    unsigned u = __float_as_uint(f);
    unsigned r = u + 0x7fffu + ((u >> 16) & 1u);
    return (ushort)(r >> 16);
}
__device__ inline float bf2f(ushort b) {
    return __uint_as_float(((unsigned)b) << 16);
}
__device__ inline ushort f2h(float f) {         // RTNE fp32 -> fp16 bits
    _Float16 h = (_Float16)f;
    ushort u;
    __builtin_memcpy(&u, &h, 2);
    return u;
}
__device__ inline float h2f(ushort u) {
    _Float16 h;
    __builtin_memcpy(&h, &u, 2);
    return (float)h;
}

// ---------------------------------------------------------------- prep (fused)
// b<64: W1 bf16 hi/lo (layer-1 A is fp32 -> bf16 path). b in [64,128): W2
// fp16 hi/lo (layer-2 A is exact fp16 -> f16 MFMA). Next nbz blocks: zero
// cnt. Last block: zero hC row n per chunk + pcnt.
__global__ __launch_bounds__(256) void prep_kernel(
    const float* __restrict__ W1, const float* __restrict__ W2,
    ushort* __restrict__ w1hi, ushort* __restrict__ w1lo,
    ushort* __restrict__ w2hf, ushort* __restrict__ w2lf,
    int* __restrict__ cnt, int* __restrict__ pcnt, int* __restrict__ galloc,
    ushort* __restrict__ hC, int n, int nbz) {
    int b = blockIdx.x, tid = threadIdx.x;
    if (b < 64) {
        int t = (b << 8) + tid;
        int k = t >> 7, nn = t & 127;
        float v = W1[t];
        ushort h = f2bf(v);
        w1hi[nn * CH + k] = h;
        w1lo[nn * CH + k] = f2bf(v - bf2f(h));
    } else if (b < 128) {
        int t = ((b - 64) << 8) + tid;
        int k = t >> 7, nn = t & 127;
        float v = W2[t];
        ushort h = f2h(v);
        w2hf[nn * CH + k] = h;
        w2lf[nn * CH + k] = f2h(v - h2f(h));
    } else if (b < 128 + nbz) {
        int i = (b - 128) * 256 + tid;
        if (i < n) cnt[i] = 0;
    } else {
        if (tid < NCHUNK * CHK) {
            int c = tid >> 5, ch = tid & 31;
            hC[((size_t)c * (n + 1) + n) * CHK + ch] = 0;
        }
        if (tid < 8) pcnt[tid] = 0;
        if (tid == 8) *galloc = 0;
    }
}

// ------------------------------------------------------- bucket + count pass
// ONE pass over edges: pack (dst<<16)|src into 8 dst-partition buckets AND
// count degrees. NEW: the cnt atomicAdd's RETURN VALUE is a free unique
// within-node index -- stored to ibuf (same bucket position). The CSR fill
// then needs NO atomics at all (the 850k contended cursor RMWs were the
// suspected gemmfill tail: MfmaUtil 3.9 / VALU 9.9 / HBM 22 -- all idle).
__global__ __launch_bounds__(256) void bucketcount_kernel(
    const int* __restrict__ src, const int* __restrict__ dst,
    unsigned* __restrict__ ebuf, unsigned char* __restrict__ ibuf,
    int* __restrict__ pcnt, int* __restrict__ cnt, int E, float p8n) {
    __shared__ int lpos[8];
    __shared__ int lbase[8];
    int tid = threadIdx.x;
    if (tid < 8) lpos[tid] = 0;
    __syncthreads();
    int i0 = (blockIdx.x * 256 + tid) * 4;
    int part[4]; int off[4]; unsigned pk[4]; int sidx[4]; int c = 0;
    if (i0 + 3 < E) {
        int4 s4 = *(const int4*)&src[i0];
        int4 d4 = *(const int4*)&dst[i0];
        int ss[4] = {s4.x, s4.y, s4.z, s4.w};
        int dd[4] = {d4.x, d4.y, d4.z, d4.w};
        c = 4;
#pragma unroll
        for (int k = 0; k < 4; k++) {
            part[k] = min(7, (int)((float)dd[k] * p8n));
            pk[k] = ((unsigned)dd[k] << 16) | (unsigned)ss[k];
            off[k] = atomicAdd(&lpos[part[k]], 1);
            sidx[k] = atomicAdd(&cnt[dd[k]], 1);   // within-node slot index
        }
    } else {
        for (int k = 0; k < 4 && i0 + k < E; k++) {
            int s = src[i0 + k], d = dst[i0 + k];
            part[c] = min(7, (int)((float)d * p8n));
            pk[c] = ((unsigned)d << 16) | (unsigned)s;
            off[c] = atomicAdd(&lpos[part[c]], 1);
            sidx[c] = atomicAdd(&cnt[d], 1);
            c++;
        }
    }
    __syncthreads();
    if (tid < 8) lbase[tid] = atomicAdd(&pcnt[tid], lpos[tid]);
    __syncthreads();
    for (int k = 0; k < c; k++) {
        int idx = lbase[part[k]] + off[k];
        if (idx < ECAP) {
            ebuf[(size_t)part[k] * ECAP + idx] = pk[k];
            ibuf[(size_t)part[k] * ECAP + idx] = (unsigned char)sidx[k];
        }
    }
}

// ---------------------------------------------------------------- place
// Dense-CSR region allocator, NO global scan: block-local LDS scan of
// round8(deg+1) + ONE global atomicAdd per block. Writes self-edge + pads.
// (cursor no longer needed -- fill is atomic-free via ibuf indices.)
__global__ __launch_bounds__(256) void place_kernel(
    const int* __restrict__ cnt, int* __restrict__ rsp,
    int* __restrict__ galloc, ushort* __restrict__ esrc, int n) {
    __shared__ int lds[256];
    __shared__ int gbase;
    int t = threadIdx.x;
    int i = blockIdx.x * 256 + t;
    int c = (i < n) ? cnt[i] : 0;
    int sz = (i < n) ? ((c + 8) & ~7) : 0;   // round8(deg+1)
    lds[t] = sz;
    __syncthreads();
    for (int off = 1; off < 256; off <<= 1) {
        int x = (t >= off) ? lds[t - off] : 0;
        __syncthreads();
        lds[t] += x;
        __syncthreads();
    }
    int incl = lds[t];
    if (t == 255) gbase = atomicAdd(galloc, incl);
    __syncthreads();
    int base = gbase + incl - sz;
    if (i < n) {
        rsp[i] = base;
        esrc[base] = (ushort)i;        // slot base holds the self-edge
        for (int p = base + 1 + c; p < base + sz; p++) esrc[p] = (ushort)n;
    }
}

// ---------------------------------------------------------------- GEMM1 body
// hA = x @ W1 (pre-scaled), bf16 hi/lo split on fp32 A (direct loads,
// R6-verified). C is FP16 chunk-major (4 chunks x 32ch, interleaved
// ch=2*col+(nt&1)) -- one packed 4B nt-store per (m,reg,chunk).
__device__ __forceinline__ void gemm1_body(
    int bx, int by, const float* __restrict__ A,
    const ushort* __restrict__ Bthi, const ushort* __restrict__ Btlo,
    const int* __restrict__ cntp, ushort* __restrict__ C16, int n_rows) {
    const int tid = threadIdx.x;
    const int bm0 = bx * 128;                // block covers 128 rows
    const int wv = tid >> 6;
    const int lane = tid & 63;
    const int col = lane & 15;     // A row-in-frag / B col / C col
    const int quad = lane >> 4;    // k-block for A/B; row-quad for C
    const int rbase = bm0 + wv * 32 + col;   // wave rows: rbase + m*16, m<2
    const int ntBase = by * 4;

    f32x4 acc[2][4];   // [m][nt]
#pragma unroll
    for (int m = 0; m < 2; m++)
#pragma unroll
        for (int t = 0; t < 4; t++) acc[m][t] = (f32x4){0.f, 0.f, 0.f, 0.f};

#pragma unroll
    for (int k0 = 0; k0 < 4; k0++) {
        const int kb = k0 * 32 + quad * 8;
        bf16x8 ah[2], al[2];
#pragma unroll
        for (int m = 0; m < 2; m++) {
            int arow = rbase + m * 16;
            bool av = (arow < n_rows);
            const float* __restrict__ Ap = A + (size_t)arow * CH + kb;
            float4 f0 = av ? *(const float4*)Ap       : make_float4(0.f, 0.f, 0.f, 0.f);
            float4 f1 = av ? *(const float4*)(Ap + 4) : make_float4(0.f, 0.f, 0.f, 0.f);
            float fa[8] = {f0.x, f0.y, f0.z, f0.w, f1.x, f1.y, f1.z, f1.w};
#pragma unroll
            for (int j = 0; j < 8; j++) {
                ushort h = f2bf(fa[j]);
                ah[m][j] = (short)h;
                al[m][j] = (short)f2bf(fa[j] - bf2f(h));
            }
        }
#pragma unroll
        for (int t = 0; t < 4; t++) {
            const int boff = ((ntBase + t) * 16 + col) * CH + kb;
            bf16x8 bh = *(const bf16x8*)&Bthi[boff];
            bf16x8 bl = *(const bf16x8*)&Btlo[boff];
#pragma unroll
            for (int m = 0; m < 2; m++) {
                acc[m][t] = __builtin_amdgcn_mfma_f32_16x16x32_bf16(ah[m], bh, acc[m][t], 0, 0, 0);
                acc[m][t] = __builtin_amdgcn_mfma_f32_16x16x32_bf16(ah[m], bl, acc[m][t], 0, 0, 0);
                acc[m][t] = __builtin_amdgcn_mfma_f32_16x16x32_bf16(al[m], bh, acc[m][t], 0, 0, 0);
            }
        }
    }

    // epilogue: C/D layout col=lane&15, row=quad*4+reg (m89-verified)
#pragma unroll
    for (int m = 0; m < 2; m++) {
#pragma unroll
        for (int reg = 0; reg < 4; reg++) {
            int gr = bm0 + wv * 32 + m * 16 + quad * 4 + reg;
            if (gr < n_rows) {
                float d = rsqrtf((float)cntp[gr] + 1.0f);
#pragma unroll
                for (int tp = 0; tp < 4; tp += 2) {
                    int nt0 = ntBase + tp;
                    int chunk = nt0 >> 1;
                    unsigned h0 = f2h(acc[m][tp][reg] * d);
                    unsigned h1 = f2h(acc[m][tp + 1][reg] * d);
                    unsigned pk = h0 | (h1 << 16);
                    __builtin_nontemporal_store(pk,
                        (unsigned*)&C16[((size_t)chunk * (n_rows + 1) + gr) * CHK
                                        + 2 * col]);
                }
            }
        }
    }
}

// ------------------------------------------------- fused GEMM1 || CSR-fill
// Blocks [0, gemmBlocks): GEMM layer 1. Blocks [gemmBlocks, +2048): the
// bucket-fed CSR fill -- now ATOMIC-FREE: slot = rsp[dst] + 1 + ibuf[e].
// Pure partition-local 2B scatter, L2-absorbed.
__global__ __launch_bounds__(256, 4) void gemmfill_kernel(
    const float* __restrict__ A, const ushort* __restrict__ Bthi,
    const ushort* __restrict__ Btlo, const int* __restrict__ cntp,
    ushort* __restrict__ C16, int n_rows, int nbx, int gemmBlocks,
    const unsigned* __restrict__ ebuf, const unsigned char* __restrict__ ibuf,
    const int* __restrict__ pcnt, const int* __restrict__ rsp,
    ushort* __restrict__ esrc) {
    int b = blockIdx.x;
    if (b < gemmBlocks) {
        gemm1_body(b % nbx, b / nbx, A, Bthi, Btlo, cntp, C16, n_rows);
    } else {
        int fb = b - gemmBlocks;              // 0..2047
        int part = fb & 7;
        int m = min(pcnt[part], ECAP);
        const unsigned* bk = ebuf + (size_t)part * ECAP;
        const unsigned char* ik = ibuf + (size_t)part * ECAP;
        for (int e = (fb >> 3) * 256 + (int)threadIdx.x; e < m; e += 256 * 256) {
            unsigned pe = bk[e];
            int idx = ik[e];
            esrc[rsp[pe >> 16] + 1 + idx] = (ushort)(pe & 0xffffu);
        }
    }
}

// ---------------------------------------------------------------- GEMM2
// hA = relu'd-bufB(fp16) @ W2 (pre-scaled). A is EXACT fp16 -> direct f16x8
// fragment loads, NO convert chain; W2 fp16 hi/lo -> 2 MFMAs per fragment.
__global__ __launch_bounds__(256, 4) void gemm2_kernel(
    const ushort* __restrict__ A16, const ushort* __restrict__ Bhf,
    const ushort* __restrict__ Blf, const int* __restrict__ cntp,
    ushort* __restrict__ C16, int n_rows) {
    const int tid = threadIdx.x;
    const int bm0 = blockIdx.x * 128;
    const int wv = tid >> 6;
    const int lane = tid & 63;
    const int col = lane & 15;
    const int quad = lane >> 4;
    const int rbase = bm0 + wv * 32 + col;
    const int ntBase = blockIdx.y * 4;
    const f16x8 fz = {0, 0, 0, 0, 0, 0, 0, 0};

    f32x4 acc[2][4];
#pragma unroll
    for (int m = 0; m < 2; m++)
#pragma unroll
        for (int t = 0; t < 4; t++) acc[m][t] = (f32x4){0.f, 0.f, 0.f, 0.f};

#pragma unroll
    for (int k0 = 0; k0 < 4; k0++) {
        const int kb = k0 * 32 + quad * 8;
        f16x8 a[2];
#pragma unroll
        for (int m = 0; m < 2; m++) {
            int arow = rbase + m * 16;
            a[m] = (arow < n_rows)
                 ? *(const f16x8*)(A16 + (size_t)arow * CH + kb) : fz;
        }
#pragma unroll
        for (int t = 0; t < 4; t++) {
            const int boff = ((ntBase + t) * 16 + col) * CH + kb;
            f16x8 bh = *(const f16x8*)&Bhf[boff];
            f16x8 bl = *(const f16x8*)&Blf[boff];
#pragma unroll
            for (int m = 0; m < 2; m++) {
                acc[m][t] = __builtin_amdgcn_mfma_f32_16x16x32_f16(a[m], bh, acc[m][t], 0, 0, 0);
                acc[m][t] = __builtin_amdgcn_mfma_f32_16x16x32_f16(a[m], bl, acc[m][t], 0, 0, 0);
            }
        }
    }

#pragma unroll
    for (int m = 0; m < 2; m++) {
#pragma unroll
        for (int reg = 0; reg < 4; reg++) {
            int gr = bm0 + wv * 32 + m * 16 + quad * 4 + reg;
            if (gr < n_rows) {
                float d = rsqrtf((float)cntp[gr] + 1.0f);
#pragma unroll
                for (int tp = 0; tp < 4; tp += 2) {
                    int nt0 = ntBase + tp;
                    int chunk = nt0 >> 1;
                    unsigned h0 = f2h(acc[m][tp][reg] * d);
                    unsigned h1 = f2h(acc[m][tp + 1][reg] * d);
                    unsigned pk = h0 | (h1 << 16);
                    __builtin_nontemporal_store(pk,
                        (unsigned*)&C16[((size_t)chunk * (n_rows + 1) + gr) * CHK
                                        + 2 * col]);
                }
            }
        }
    }
}

// ---------------------------------------------------------------- CSR gather
// fp16 h: 4 chunks of 32ch, 64B rows; 4 random lines/edge (R12-verified
// MSHR-floor halving). Output FP16 row-major, RELU at store.
__global__ __launch_bounds__(256) void gather_kernel(
    const int* __restrict__ rsp, const int* __restrict__ cnt,
    const ushort* __restrict__ esrc, const ushort* __restrict__ hC16,
    const float* __restrict__ bias, ushort* __restrict__ out16, int n) {
    int c = blockIdx.x & 3;
    int bic = blockIdx.x >> 2;
    int wv = threadIdx.x >> 6;
    int lane = threadIdx.x & 63;
    int g = lane >> 2;    // node slot 0..15
    int q = lane & 3;     // 16B quarter of the 64B row
    int i = bic * 64 + wv * 16 + g;
    bool valid = (i < n);
    int iw = valid ? i : 0;
    const f16x8* __restrict__ h8 = (const f16x8*)(hC16 + (size_t)c * (n + 1) * CHK);

    // sequential L2 pre-warm: one float4 per thread covers the 3.2MB slice
    float warm = 0.f;
    {
        int nbr = (n + 63) >> 6;                        // blocks per chunk
        const float4* __restrict__ w4 = (const float4*)h8;
        size_t p = (size_t)bic * 256 + threadIdx.x;
        size_t sliceF4 = ((size_t)(n + 1) * CHK) >> 3;  // 2B elems /8 = float4
        for (; p < sliceF4; p += (size_t)nbr * 256) {
            float4 v = w4[p];
            warm += v.x + v.y + v.z + v.w;
        }
    }

    int beg = valid ? rsp[iw] : 0;
    int cv  = valid ? cnt[iw] : -8;
    int pc  = (cv + 8) & ~7;          // round8(deg+1); 0 for invalid
    float accA[4] = {0.f, 0.f, 0.f, 0.f};
    float accB[4] = {0.f, 0.f, 0.f, 0.f};
    for (int j = beg; j < beg + pc; j += 8) {   // beg is a multiple of 8
        ushort4 e0 = *(const ushort4*)&esrc[j];
        ushort4 e1 = *(const ushort4*)&esrc[j + 4];
        f16x8 v0 = h8[(size_t)e0.x * 4 + q];
        f16x8 v1 = h8[(size_t)e0.y * 4 + q];
        f16x8 v2 = h8[(size_t)e0.z * 4 + q];
        f16x8 v3 = h8[(size_t)e0.w * 4 + q];
        f16x8 v4 = h8[(size_t)e1.x * 4 + q];
        f16x8 v5 = h8[(size_t)e1.y * 4 + q];
        f16x8 v6 = h8[(size_t)e1.z * 4 + q];
        f16x8 v7 = h8[(size_t)e1.w * 4 + q];
#pragma unroll
        for (int s = 0; s < 4; s++) {
            accA[s] += (float)v0[2 * s]; accB[s] += (float)v0[2 * s + 1];
            accA[s] += (float)v1[2 * s]; accB[s] += (float)v1[2 * s + 1];
            accA[s] += (float)v2[2 * s]; accB[s] += (float)v2[2 * s + 1];
            accA[s] += (float)v3[2 * s]; accB[s] += (float)v3[2 * s + 1];
            accA[s] += (float)v4[2 * s]; accB[s] += (float)v4[2 * s + 1];
            accA[s] += (float)v5[2 * s]; accB[s] += (float)v5[2 * s + 1];
            accA[s] += (float)v6[2 * s]; accB[s] += (float)v6[2 * s + 1];
            accA[s] += (float)v7[2 * s]; accB[s] += (float)v7[2 * s + 1];
        }
    }
    // keep the warm loads alive (cannot be DCE'd)
    __asm__ volatile("" : : "v"(warm));
    if (valid) {
        // lane q's halves: even ch -> 32c+4q+s, odd -> 32c+16+4q+s (s=0..3)
        float di = rsqrtf((float)cv + 1.0f);
        const float4* bias4 = (const float4*)bias;
        float4 bvA = bias4[8 * c + q];
        float4 bvB = bias4[8 * c + 4 + q];
        u16x4 pA, pB;
        pA[0] = f2h(fmaxf(bvA.x + di * accA[0], 0.f));
        pA[1] = f2h(fmaxf(bvA.y + di * accA[1], 0.f));
        pA[2] = f2h(fmaxf(bvA.z + di * accA[2], 0.f));
        pA[3] = f2h(fmaxf(bvA.w + di * accA[3], 0.f));
        pB[0] = f2h(fmaxf(bvB.x + di * accB[0], 0.f));
        pB[1] = f2h(fmaxf(bvB.y + di * accB[1], 0.f));
        pB[2] = f2h(fmaxf(bvB.z + di * accB[2], 0.f));
        pB[3] = f2h(fmaxf(bvB.w + di * accB[3], 0.f));
        ushort* o16 = out16 + (size_t)iw * CH + 32 * c + 4 * q;
        __builtin_nontemporal_store(pA, (u16x4*)o16);
        __builtin_nontemporal_store(pB, (u16x4*)(o16 + 16));
    }
}

// ---------------------------------------------------------------- head
// out = relu(bufB) @ Wh + bh. bufB is fp16 (already relu'd; fmax kept --
// idempotent). One f16x8 load per thread fills the 16x128 LDS tile.
__global__ __launch_bounds__(256) void head_kernel(
    const ushort* __restrict__ A16, const float* __restrict__ Wh,
    const float* __restrict__ bh, float* __restrict__ out, int n) {
    __shared__ float Ws[CH * NCLS];
    __shared__ float As[16][129];
    const int tid = threadIdx.x;
    const int n0 = blockIdx.x * 16;
#pragma unroll
    for (int i = 0; i < 8; i++) {
        int l = tid + i * 256;
        Ws[l] = Wh[l];
    }
    {
        int row = tid >> 4, c0 = (tid & 15) * 8;
        int gr = n0 + row;
        const f16x8 fz = {0, 0, 0, 0, 0, 0, 0, 0};
        f16x8 v = (gr < n) ? *(const f16x8*)(A16 + (size_t)gr * CH + c0) : fz;
#pragma unroll
        for (int j = 0; j < 8; j++) As[row][c0 + j] = fmaxf((float)v[j], 0.0f);
    }
    __syncthreads();
    int r = tid >> 4, c = tid & 15;
    float acc = bh[c];
#pragma unroll
    for (int k = 0; k < CH; k++) acc = fmaf(As[r][k], Ws[k * NCLS + c], acc);
    int gr = n0 + r;
    if (gr < n) out[(size_t)gr * NCLS + c] = acc;
}

// ---------------------------------------------------------------- launch
extern "C" void kernel_launch(void* const* d_in, const int* in_sizes, int n_in,
                              void* d_out, int out_size, void* d_ws, size_t ws_size,
                              hipStream_t stream) {
    const float* x  = (const float*)d_in[0];
    const int*   ei = (const int*)d_in[1];
    const float* W1 = (const float*)d_in[2];
    const float* b1 = (const float*)d_in[3];
    const float* W2 = (const float*)d_in[4];
    const float* b2 = (const float*)d_in[5];
    const float* Wh = (const float*)d_in[6];
    const float* bh = (const float*)d_in[7];
    float* out = (float*)d_out;

    const int n = in_sizes[0] / CH;   // 50000
    const int E = in_sizes[1] / 2;    // 800000
    const int* src = ei;
    const int* dst = ei + E;

    // workspace layout (all chunks 16B aligned)
    ushort* w1hi = (ushort*)d_ws;                    // 16384 each
    ushort* w1lo = w1hi + CH * CH;
    ushort* w2hf = w1lo + CH * CH;                   // fp16 hi
    ushort* w2lf = w2hf + CH * CH;                   // fp16 lo
    ushort* hA   = w2lf + CH * CH;                   // fp16 (n+1)*128 chunk-major
    ushort* bufB = hA + (size_t)(n + 1) * CH;        // fp16 n*128 row-major
    int* cnt    = (int*)(bufB + (size_t)n * CH);     // n  (in-degrees)
    int* rsp    = cnt + n;                           // n  (region starts)
    int* pcnt   = rsp + n;                           // 8
    int* galloc = pcnt + 8;                          // 1 (+7 pad)
    ushort* esrc = (ushort*)(pcnt + 16);             // <= E + 8n padded edges
    unsigned* ebuf = (unsigned*)bufB;                // 8*ECAP*4B = 4MB, aliases
    unsigned char* ibuf = (unsigned char*)bufB + (size_t)8 * ECAP * 4;  // +1MB
                                                     // (bufB dead till gather1)

    const int B = 256;
    const int nbz = (n + B - 1) / B;                 // cnt-zero / place blocks
    const int nbx = (n + 127) / 128;                 // gemm x-blocks (391)
    const int gemmBlocks = nbx * 2;                  // 782
    const int nbr = (n + 63) / 64;                   // 782 node ranges
    const int gatherGrid = NCHUNK * nbr;             // 3128
    const float p8n = 8.0f / (float)n;               // partition map scale

    // ---- build: bucket+count+idx (1 edge pass) -> place (block allocator)
    prep_kernel<<<128 + nbz + 1, B, 0, stream>>>(W1, W2, w1hi, w1lo, w2hf, w2lf,
                                                 cnt, pcnt, galloc, hA, n, nbz);
    bucketcount_kernel<<<(E + 1023) / 1024, B, 0, stream>>>(src, dst, ebuf, ibuf,
                                                            pcnt, cnt, E, p8n);
    place_kernel<<<nbz, B, 0, stream>>>(cnt, rsp, galloc, esrc, n);

    // layer 1 (gemm || atomic-free csr-fill fused)
    gemmfill_kernel<<<gemmBlocks + 2048, B, 0, stream>>>(
        x, w1hi, w1lo, cnt, hA, n, nbx, gemmBlocks, ebuf, ibuf, pcnt, rsp, esrc);
    gather_kernel<<<gatherGrid, B, 0, stream>>>(rsp, cnt, esrc, hA, b1, bufB, n);
    // layer 2 (native f16 MFMA, fp16 A direct loads)
    gemm2_kernel<<<dim3(nbx, 2), B, 0, stream>>>(bufB, w2hf, w2lf, cnt, hA, n);
    gather_kernel<<<gatherGrid, B, 0, stream>>>(rsp, cnt, esrc, hA, b2, bufB, n);
    // head
    head_kernel<<<(n + 15) / 16, B, 0, stream>>>(bufB, Wh, bh, out, n);
}